// Round 9
// baseline (173.082 us; speedup 1.0000x reference)
//
#include <hip/hip_runtime.h>

// LTC cell: B=1024, I=128, N=256, 6 unfolds. Round 13: R12 packed-fp32 body
// + IN-WAVE REDUCE AT 16-LANE GRANULE. Wave = 4 i-slices x 16 consecutive
// n-columns (n = w*16 + lane&15, ih = lane>>4): global loads stay 4x256B
// contiguous chunks (same 16 cache lines/wave as R0 -- R9's mistake was a
// 1-lane granule = 64 lines), while the 4 (bb,n) partials sit at lane
// stride 16 -> 2-step shfl_xor(16)/shfl_xor(32) butterfly replaces the
// part[] LDS reduce. part[] (32KB) deleted; barriers 13 -> 6 (fill + one
// vt-visibility barrier per unfold; sensory reduce barrier-free). vt/xs
// padded one float4 per slice (index i+ih, compile-time fold) so the 4-addr
// ds_read broadcast is bank-conflict-free. Model: issue ~110 cyc/iter
// (unchanged), busy 72% -> ~80% from barrier-count halving.

#define LOG2E 1.44269504088896340f

constexpr int Bn = 1024;
constexpr int In = 128;
constexpr int Nn = 256;
constexpr int UNFOLDS = 6;

typedef float v2f __attribute__((ext_vector_type(2)));

#if __has_builtin(__builtin_amdgcn_exp2f)
#define EXP2F(x) __builtin_amdgcn_exp2f(x)
#else
#define EXP2F(x) __exp2f(x)
#endif
#if __has_builtin(__builtin_amdgcn_rcpf)
#define RCPF(x) __builtin_amdgcn_rcpf(x)
#else
#define RCPF(x) (1.0f / (x))
#endif

__device__ __forceinline__ v2f shfl_xor2(v2f x, int m) {
    return (v2f){__shfl_xor(x.x, m, 64), __shfl_xor(x.y, m, 64)};
}

// ---------------------------------------------------------------------------
// Pack: Prec[i*N+n] = {sigma*log2e, sigma*mu*log2e, W, W*erev}; same for Psen.
// sigmoid(sigma*(v-mu)) = 1/(1 + exp2(B - A*v)), A=sigma*log2e, B=sigma*mu*log2e.
// ---------------------------------------------------------------------------
__global__ __launch_bounds__(256) void pack_kernel(
    const float* __restrict__ mu, const float* __restrict__ sigma,
    const float* __restrict__ W, const float* __restrict__ erev,
    const float* __restrict__ smu, const float* __restrict__ ssigma,
    const float* __restrict__ sW, const float* __restrict__ serev,
    float4* __restrict__ Prec, float4* __restrict__ Psen) {
    int idx = blockIdx.x * 256 + threadIdx.x;
    if (idx < Nn * Nn) {
        float s = sigma[idx], m = mu[idx], w = W[idx], e = erev[idx];
        Prec[idx] = make_float4(s * LOG2E, s * m * LOG2E, w, w * e);
        return;
    }
    int j = idx - Nn * Nn;
    if (j < In * Nn) {
        float s = ssigma[j], m = smu[j], w = sW[j], e = serev[j];
        Psen[j] = make_float4(s * LOG2E, s * m * LOG2E, w, w * e);
    }
}

// ---------------------------------------------------------------------------
// Fused LTC kernel: sensory + 6 unfolds. Grid = 256 blocks x 1024 threads.
// Thread: w = tid>>6, lane = tid&63, nl = lane&15, ih = lane>>4 (i-slice AND
// owned batch), n = w*16 + nl. Inner quad in packed fp32 (R12 body).
// ---------------------------------------------------------------------------
__global__ __launch_bounds__(1024, 1) void ltc_fused_kernel(
    const float* __restrict__ inputs, const float* __restrict__ state,
    const float* __restrict__ input_w, const float* __restrict__ input_b,
    const float4* __restrict__ Psen, const float4* __restrict__ Prec,
    const float* __restrict__ vleak, const float* __restrict__ gleak,
    const float* __restrict__ cmt, float* __restrict__ out) {
    __shared__ float4 vt[2][260];        // ping-pong v, +1 row pad per slice
    __shared__ float4 xs[132];           // sensory x, +1 row pad per slice

    const int tid  = threadIdx.x;
    const int b0   = blockIdx.x * 4;
    const int lane = tid & 63;
    const int w    = tid >> 6;
    const int nl   = lane & 15;
    const int ih   = lane >> 4;          // 0..3 : i-slice AND owned batch
    const int n    = w * 16 + nl;        // column 0..255

    // ---- fill: v state (this thread's (bb=ih, n)) + sensory x ----
    float vp = state[(b0 + ih) * Nn + n];          // 4x64B per wave
    ((float*)&vt[0][n + (n >> 6)])[ih] = vp;
    if (tid < 512) {
        int i = tid & 127, bb = tid >> 7;          // bb in 0..3
        ((float*)&xs[i + (i >> 5)])[bb] =
            inputs[(b0 + bb) * In + i] * input_w[i] + input_b[i];
    }
    const float g = gleak[n], c = cmt[n];
    const float gvl = g * vleak[n];
    __syncthreads();

    // ---- sensory sums (32 i per thread; in-wave reduce, no barrier) ----
    v2f sens;                            // {den, num} for (bb=ih, n)
    {
        v2f acc0 = {0.f, 0.f}, acc1 = {0.f, 0.f};
        v2f acc2 = {0.f, 0.f}, acc3 = {0.f, 0.f};
        const float4* __restrict__ pp = Psen + n;
#pragma unroll 8
        for (int ii = 0; ii < 32; ++ii) {
            int i = ih * 32 + ii;
            float4 p = pp[i * Nn];       // 4x256B contiguous chunks per wave
            float4 v = xs[i + ih];       // padded broadcast (i>>5 == ih)
            v2f AA = {p.x, p.x};
            v2f BB = {p.y, p.y};
            v2f WW = {p.z, p.w};
            v2f u01 = __builtin_elementwise_fma(-AA, (v2f){v.x, v.y}, BB);
            v2f u23 = __builtin_elementwise_fma(-AA, (v2f){v.z, v.w}, BB);
            v2f a01 = (v2f){EXP2F(u01.x), EXP2F(u01.y)} + 1.0f;
            v2f a23 = (v2f){EXP2F(u23.x), EXP2F(u23.y)} + 1.0f;
            float r0 = RCPF(a01.x), r1 = RCPF(a01.y);
            float r2 = RCPF(a23.x), r3 = RCPF(a23.y);
            acc0 = __builtin_elementwise_fma(WW, (v2f){r0, r0}, acc0);
            acc1 = __builtin_elementwise_fma(WW, (v2f){r1, r1}, acc1);
            acc2 = __builtin_elementwise_fma(WW, (v2f){r2, r2}, acc2);
            acc3 = __builtin_elementwise_fma(WW, (v2f){r3, r3}, acc3);
        }
        acc0 += shfl_xor2(acc0, 16);
        acc1 += shfl_xor2(acc1, 16);
        acc2 += shfl_xor2(acc2, 16);
        acc3 += shfl_xor2(acc3, 16);
        acc0 += shfl_xor2(acc0, 32);
        acc1 += shfl_xor2(acc1, 32);
        acc2 += shfl_xor2(acc2, 32);
        acc3 += shfl_xor2(acc3, 32);
        sens = (ih == 0) ? acc0 : (ih == 1) ? acc1 : (ih == 2) ? acc2 : acc3;
    }

    // ---- 6 unfolds: ONE barrier each (vt visibility), in-wave reduce ----
    const float4* __restrict__ pp = Prec + n;
    int cur = 0;
    for (int s = 0; s < UNFOLDS; ++s) {
        v2f acc0 = {0.f, 0.f}, acc1 = {0.f, 0.f};
        v2f acc2 = {0.f, 0.f}, acc3 = {0.f, 0.f};
        const float4* __restrict__ vc = vt[cur];
#pragma unroll 8
        for (int ii = 0; ii < 64; ++ii) {
            int i = ih * 64 + ii;
            float4 p = pp[i * Nn];       // 4x256B chunks (L2-resident stream)
            float4 v = vc[i + ih];       // padded broadcast (i>>6 == ih)
            v2f AA = {p.x, p.x};
            v2f BB = {p.y, p.y};
            v2f WW = {p.z, p.w};
            v2f u01 = __builtin_elementwise_fma(-AA, (v2f){v.x, v.y}, BB);
            v2f u23 = __builtin_elementwise_fma(-AA, (v2f){v.z, v.w}, BB);
            v2f a01 = (v2f){EXP2F(u01.x), EXP2F(u01.y)} + 1.0f;
            v2f a23 = (v2f){EXP2F(u23.x), EXP2F(u23.y)} + 1.0f;
            float r0 = RCPF(a01.x), r1 = RCPF(a01.y);
            float r2 = RCPF(a23.x), r3 = RCPF(a23.y);
            acc0 = __builtin_elementwise_fma(WW, (v2f){r0, r0}, acc0);
            acc1 = __builtin_elementwise_fma(WW, (v2f){r1, r1}, acc1);
            acc2 = __builtin_elementwise_fma(WW, (v2f){r2, r2}, acc2);
            acc3 = __builtin_elementwise_fma(WW, (v2f){r3, r3}, acc3);
        }
        acc0 += shfl_xor2(acc0, 16);
        acc1 += shfl_xor2(acc1, 16);
        acc2 += shfl_xor2(acc2, 16);
        acc3 += shfl_xor2(acc3, 16);
        acc0 += shfl_xor2(acc0, 32);
        acc1 += shfl_xor2(acc1, 32);
        acc2 += shfl_xor2(acc2, 32);
        acc3 += shfl_xor2(acc3, 32);
        v2f a = (ih == 0) ? acc0 : (ih == 1) ? acc1 : (ih == 2) ? acc2 : acc3;

        float wn = sens.y + a.y;         // num
        float wd = sens.x + a.x;         // den
        float res = (c * vp + gvl + wn) * RCPF(c + g + wd);
        vp = res;
        if (s == UNFOLDS - 1) {
            out[(b0 + ih) * Nn + n] = res;               // final store
        } else {
            ((float*)&vt[cur ^ 1][n + (n >> 6)])[ih] = res;
            __syncthreads();             // vt[next] visible; WAR-safe by
                                         // ping-pong (see R13 analysis)
        }
        cur ^= 1;
    }
}

// ---------------------------------------------------------------------------
extern "C" void kernel_launch(void* const* d_in, const int* in_sizes, int n_in,
                              void* d_out, int out_size, void* d_ws, size_t ws_size,
                              hipStream_t stream) {
    const float* inputs   = (const float*)d_in[0];
    const float* state    = (const float*)d_in[1];
    const float* input_w  = (const float*)d_in[2];
    const float* input_b  = (const float*)d_in[3];
    const float* smu      = (const float*)d_in[4];
    const float* ssigma   = (const float*)d_in[5];
    const float* sW       = (const float*)d_in[6];
    const float* serev    = (const float*)d_in[7];
    const float* mu       = (const float*)d_in[8];
    const float* sigma    = (const float*)d_in[9];
    const float* W        = (const float*)d_in[10];
    const float* erev     = (const float*)d_in[11];
    const float* vleak    = (const float*)d_in[12];
    const float* gleak    = (const float*)d_in[13];
    const float* cmt      = (const float*)d_in[14];
    float* out = (float*)d_out;

    // Workspace: Prec 1 MiB | Psen 512 KiB
    char* ws = (char*)d_ws;
    float4* Prec = (float4*)ws;
    float4* Psen = (float4*)(ws + (1u << 20));

    pack_kernel<<<(Nn * Nn + In * Nn + 255) / 256, 256, 0, stream>>>(
        mu, sigma, W, erev, smu, ssigma, sW, serev, Prec, Psen);

    ltc_fused_kernel<<<Bn / 4, 1024, 0, stream>>>(
        inputs, state, input_w, input_b, Psen, Prec, vleak, gleak, cmt, out);
}